// Round 3
// baseline (186.052 us; speedup 1.0000x reference)
//
#include <hip/hip_runtime.h>
#include <math.h>

// ---------------------------------------------------------------------------
// NormalDistributionChecker1D, round 3.
// Pass 1: sum/sumsq; contiguous per-block chunks, 8 named in-flight dwordx4.
// Pass 2: band-limited soft histogram. For a = 144.27*z, sigmoid_k is exactly
//   0/1 (to <2e-8) unless |a - C_k| <= 26; at most 2 thresholds are in-band.
//   Per element: 1 exp2 + 2 rcp instead of 9 exp2 + 9 rcp.
//   Bookkeeping: A[j] += s0, B[j] += s1 (boundary values), n_m = #(a > T_m)
//   (saturation counts). finalize stitches cum[k] = A[k]+B[k-1]+(n-N[k-2]).
// Pass 3: scalar fp64 epilogue (chi2, softmax interp).
// Accumulation: fp32/int per-lane -> fp64/int wave+block reduce -> fixed-point
// (x 2^20) / integer device atomics: deterministic across graph replays.
// ---------------------------------------------------------------------------

#if __has_builtin(__builtin_amdgcn_exp2f)
#define EXP2F(x) __builtin_amdgcn_exp2f(x)
#else
#define EXP2F(x) exp2f(x)
#endif
#if __has_builtin(__builtin_amdgcn_rcpf)
#define RCPF(x) __builtin_amdgcn_rcpf(x)
#else
#define RCPF(x) (1.0f / (x))
#endif

#define FIXED_SCALE 1048576.0  // 2^20

// C_k = 144.26950408889634 * zscore_k ; sentinel C_9 = 1e9 (j==9 -> no match)
__device__ __constant__ float d_C[10] = {
    -184.888834f, -121.420293f, -75.655000f, -36.550261f, 0.0f,
    36.550261f, 75.655000f, 121.420293f, 184.888834f, 1.0e9f};
// Saturation compare thresholds T_m = C_m + 26
#define T0 (-158.888834f)
#define T1 (-95.420293f)
#define T2 (-49.655000f)
#define T3 (-10.550261f)
#define T4 (26.0f)
#define T5 (62.550261f)
#define T6 (101.655000f)
#define T7 (147.420293f)
#define T8 (210.888834f)

static __device__ __forceinline__ double wave_reduce_d(double v) {
#pragma unroll
    for (int off = 32; off > 0; off >>= 1) v += __shfl_down(v, off);
    return v;
}
static __device__ __forceinline__ int wave_reduce_i(int v) {
#pragma unroll
    for (int off = 32; off > 0; off >>= 1) v += __shfl_down(v, off);
    return v;
}

static __device__ __forceinline__ void atomic_add_fixed(long long* addr, double v) {
    long long q = (long long)llround(v * FIXED_SCALE);
    atomicAdd((unsigned long long*)addr, (unsigned long long)q);
}

// ws layout (long long):
// [0]=sum [1]=sumsq [2..10]=A[0..8] [11..19]=B[0..8] [20..26]=Ncnt[0..6]
__global__ __launch_bounds__(256) void pass1_stats(const float* __restrict__ x,
                                                   long long* __restrict__ ws, int n) {
    const int tx = threadIdx.x;
    const int n4 = n >> 2;
    const float4* __restrict__ x4 = (const float4*)x;
    const int per_block = (n4 + gridDim.x - 1) / gridDim.x;
    const int i0 = blockIdx.x * per_block + tx;
    const int iend = min((blockIdx.x + 1) * per_block, n4);

    float fs = 0.f, fss = 0.f;
    int i = i0;
    // 8 NAMED loads -> 8 dwordx4 genuinely in flight (round-2's v[8] array
    // collapsed to serial loads: VGPR_Count was 32).
    for (; i + 7 * 256 < iend; i += 8 * 256) {
        float4 r0 = x4[i];
        float4 r1 = x4[i + 256];
        float4 r2 = x4[i + 512];
        float4 r3 = x4[i + 768];
        float4 r4 = x4[i + 1024];
        float4 r5 = x4[i + 1280];
        float4 r6 = x4[i + 1536];
        float4 r7 = x4[i + 1792];
        fs += (r0.x + r0.y) + (r0.z + r0.w);
        fss = fmaf(r0.x, r0.x, fss); fss = fmaf(r0.y, r0.y, fss);
        fss = fmaf(r0.z, r0.z, fss); fss = fmaf(r0.w, r0.w, fss);
        fs += (r1.x + r1.y) + (r1.z + r1.w);
        fss = fmaf(r1.x, r1.x, fss); fss = fmaf(r1.y, r1.y, fss);
        fss = fmaf(r1.z, r1.z, fss); fss = fmaf(r1.w, r1.w, fss);
        fs += (r2.x + r2.y) + (r2.z + r2.w);
        fss = fmaf(r2.x, r2.x, fss); fss = fmaf(r2.y, r2.y, fss);
        fss = fmaf(r2.z, r2.z, fss); fss = fmaf(r2.w, r2.w, fss);
        fs += (r3.x + r3.y) + (r3.z + r3.w);
        fss = fmaf(r3.x, r3.x, fss); fss = fmaf(r3.y, r3.y, fss);
        fss = fmaf(r3.z, r3.z, fss); fss = fmaf(r3.w, r3.w, fss);
        fs += (r4.x + r4.y) + (r4.z + r4.w);
        fss = fmaf(r4.x, r4.x, fss); fss = fmaf(r4.y, r4.y, fss);
        fss = fmaf(r4.z, r4.z, fss); fss = fmaf(r4.w, r4.w, fss);
        fs += (r5.x + r5.y) + (r5.z + r5.w);
        fss = fmaf(r5.x, r5.x, fss); fss = fmaf(r5.y, r5.y, fss);
        fss = fmaf(r5.z, r5.z, fss); fss = fmaf(r5.w, r5.w, fss);
        fs += (r6.x + r6.y) + (r6.z + r6.w);
        fss = fmaf(r6.x, r6.x, fss); fss = fmaf(r6.y, r6.y, fss);
        fss = fmaf(r6.z, r6.z, fss); fss = fmaf(r6.w, r6.w, fss);
        fs += (r7.x + r7.y) + (r7.z + r7.w);
        fss = fmaf(r7.x, r7.x, fss); fss = fmaf(r7.y, r7.y, fss);
        fss = fmaf(r7.z, r7.z, fss); fss = fmaf(r7.w, r7.w, fss);
    }
    for (; i < iend; i += 256) {
        float4 v = x4[i];
        fs += (v.x + v.y) + (v.z + v.w);
        fss = fmaf(v.x, v.x, fss); fss = fmaf(v.y, v.y, fss);
        fss = fmaf(v.z, v.z, fss); fss = fmaf(v.w, v.w, fss);
    }
    if (blockIdx.x == 0 && tx == 0) {  // n%4 scalar tail (empty at n=16.7M)
        for (int j = n4 << 2; j < n; ++j) {
            float v = x[j];
            fs += v;
            fss = fmaf(v, v, fss);
        }
    }

    double s = wave_reduce_d((double)fs);
    double ss = wave_reduce_d((double)fss);
    __shared__ double sm[4][2];
    const int lane = tx & 63, wid = tx >> 6;
    if (lane == 0) { sm[wid][0] = s; sm[wid][1] = ss; }
    __syncthreads();
    if (tx == 0) {
        double ts = 0, tss = 0;
#pragma unroll
        for (int w = 0; w < 4; ++w) { ts += sm[w][0]; tss += sm[w][1]; }
        atomic_add_fixed(&ws[0], ts);
        atomic_add_fixed(&ws[1], tss);
    }
}

__global__ __launch_bounds__(256) void pass2_cum(const float* __restrict__ x,
                                                 const long long* __restrict__ ws_stats,
                                                 long long* __restrict__ ws, int n) {
    const double Ld = 144.26950408889634;  // 100 * log2(e)
    const double nd = (double)n;
    const double s = (double)ws_stats[0] / FIXED_SCALE;
    const double ss = (double)ws_stats[1] / FIXED_SCALE;
    const double mean = s / nd;
    const double var = (ss - s * s / nd) / (nd - 1.0);  // ddof=1
    const double inv_std = 1.0 / sqrt(var);
    const float S = (float)(Ld * inv_std);
    const float B = (float)(-Ld * inv_std * mean);

    // LDS LUT: (C_j, G_j = 2^(C_j - C_{j+1})) for the boundary-pair shortcut.
    __shared__ float2 lut[10];
    if (threadIdx.x == 0) {
#pragma unroll
        for (int j = 0; j < 10; ++j) {
            float cj = d_C[j];
            float g = (j < 9) ? exp2f(cj - d_C[j + 1]) : 1.0f;
            lut[j] = make_float2(cj, g);
        }
    }
    __syncthreads();

    float accA[9], accB[9];
    int nm[7];
#pragma unroll
    for (int k = 0; k < 9; ++k) { accA[k] = 0.f; accB[k] = 0.f; }
#pragma unroll
    for (int m = 0; m < 7; ++m) nm[m] = 0;

    auto process = [&](float xv) {
        const float a = fmaf(xv, S, B);  // a = 144.27 * z
        const bool c0 = a > T0, c1 = a > T1, c2 = a > T2, c3 = a > T3;
        const bool c4 = a > T4, c5 = a > T5, c6 = a > T6, c7 = a > T7;
        const bool c8 = a > T8;
        const int j = (int)c0 + (int)c1 + (int)c2 + (int)c3 + (int)c4 +
                      (int)c5 + (int)c6 + (int)c7 + (int)c8;
        nm[0] += c0; nm[1] += c1; nm[2] += c2; nm[3] += c3;
        nm[4] += c4; nm[5] += c5; nm[6] += c6;
        const float2 cg = lut[j];
        const float e0 = EXP2F(a - cg.x);   // boundary j   (e0 <= 2^26, no inf)
        const float e1 = e0 * cg.y;         // boundary j+1
        const float s0 = RCPF(1.0f + e0);
        const float s1 = RCPF(1.0f + e1);
#pragma unroll
        for (int k = 0; k < 9; ++k) {
            accA[k] += (j == k) ? s0 : 0.0f;
            accB[k] += (j == k) ? s1 : 0.0f;
        }
    };

    const int tx = threadIdx.x;
    const int n4 = n >> 2;
    const float4* __restrict__ x4 = (const float4*)x;
    const int per_block = (n4 + gridDim.x - 1) / gridDim.x;
    const int i0 = blockIdx.x * per_block + tx;
    const int iend = min((blockIdx.x + 1) * per_block, n4);

    int i = i0;
    for (; i + 3 * 256 < iend; i += 4 * 256) {
        float4 r0 = x4[i];
        float4 r1 = x4[i + 256];
        float4 r2 = x4[i + 512];
        float4 r3 = x4[i + 768];
        process(r0.x); process(r0.y); process(r0.z); process(r0.w);
        process(r1.x); process(r1.y); process(r1.z); process(r1.w);
        process(r2.x); process(r2.y); process(r2.z); process(r2.w);
        process(r3.x); process(r3.y); process(r3.z); process(r3.w);
    }
    for (; i < iend; i += 256) {
        float4 v = x4[i];
        process(v.x); process(v.y); process(v.z); process(v.w);
    }
    if (blockIdx.x == 0 && tx == 0) {  // n%4 scalar tail (empty at n=16.7M)
        for (int jj = n4 << 2; jj < n; ++jj) process(x[jj]);
    }

    // wave -> block -> global reduction
    __shared__ double smA[4][9], smB[4][9];
    __shared__ int smN[4][7];
    const int lane = tx & 63, wid = tx >> 6;
#pragma unroll
    for (int k = 0; k < 9; ++k) {
        double ra = wave_reduce_d((double)accA[k]);
        double rb = wave_reduce_d((double)accB[k]);
        if (lane == 0) { smA[wid][k] = ra; smB[wid][k] = rb; }
    }
#pragma unroll
    for (int m = 0; m < 7; ++m) {
        int rn = wave_reduce_i(nm[m]);
        if (lane == 0) smN[wid][m] = rn;
    }
    __syncthreads();
    if (tx < 9) {
        double ta = smA[0][tx] + smA[1][tx] + smA[2][tx] + smA[3][tx];
        double tb = smB[0][tx] + smB[1][tx] + smB[2][tx] + smB[3][tx];
        atomic_add_fixed(&ws[2 + tx], ta);
        atomic_add_fixed(&ws[11 + tx], tb);
    } else if (tx >= 16 && tx < 23) {
        const int m = tx - 16;
        long long tn = (long long)(smN[0][m] + smN[1][m] + smN[2][m] + smN[3][m]);
        atomicAdd((unsigned long long*)&ws[20 + m], (unsigned long long)tn);
    }
}

__global__ void finalize_kernel(const long long* __restrict__ ws, float* __restrict__ out,
                                int n) {
    const double CRIT[9] = {14.683657, 12.242145, 10.656372, 9.413640, 8.342832,
                            7.357034,  6.393306,  5.380053,  4.168159};
    const double nd = (double)n;
    double A[9], Bv[9];
#pragma unroll
    for (int k = 0; k < 9; ++k) {
        A[k] = (double)ws[2 + k] / FIXED_SCALE;
        Bv[k] = (double)ws[11 + k] / FIXED_SCALE;
    }
    double Ncnt[7];
#pragma unroll
    for (int m = 0; m < 7; ++m) Ncnt[m] = (double)ws[20 + m];

    // stitch: cum[k] = A[k] + B[k-1] + #(saturated-to-1) = A[k]+B[k-1]+(n-N[k-2])
    double cum[9];
    cum[0] = A[0];
    cum[1] = A[1] + Bv[0];
#pragma unroll
    for (int k = 2; k < 9; ++k) cum[k] = A[k] + Bv[k - 1] + (nd - Ncnt[k - 2]);

    double actual[10];
    actual[0] = cum[0];
#pragma unroll
    for (int k = 1; k < 9; ++k) actual[k] = cum[k] - cum[k - 1];
    actual[9] = nd - cum[8];

    const double expected = nd * (double)0.1f;
    const double denom = expected + 1e-7;
    double chi2 = 0.0;
#pragma unroll
    for (int j = 0; j < 10; ++j) {
        double d = actual[j] - expected;
        chi2 += d * d / denom;
    }

    double dneg[9], m = -1e300;
#pragma unroll
    for (int k = 0; k < 9; ++k) {
        dneg[k] = -fabs(chi2 - CRIT[k]);
        if (dneg[k] > m) m = dneg[k];
    }
    double W = 0.0, PQ = 0.0;
#pragma unroll
    for (int k = 0; k < 9; ++k) {
        double w = exp(dneg[k] - m);
        W += w;
        PQ += w * (0.1 * (double)(k + 1));
    }
    double p = 1.0 - PQ / W;
    double excess = (chi2 - 14.683657) / 100.0;
    if (excess < 0.0) excess = 0.0;
    out[0] = (float)(p + excess);
}

extern "C" void kernel_launch(void* const* d_in, const int* in_sizes, int n_in,
                              void* d_out, int out_size, void* d_ws, size_t ws_size,
                              hipStream_t stream) {
    const float* x = (const float*)d_in[0];
    const int n = in_sizes[0];
    long long* ws = (long long*)d_ws;

    hipMemsetAsync(d_ws, 0, 32 * sizeof(long long), stream);

    pass1_stats<<<2048, 256, 0, stream>>>(x, ws, n);
    pass2_cum<<<1024, 256, 0, stream>>>(x, ws, ws, n);
    finalize_kernel<<<1, 1, 0, stream>>>(ws, (float*)d_out, n);
}

// Round 4
// 169.076 us; speedup vs baseline: 1.1004x; 1.1004x over previous
//
#include <hip/hip_runtime.h>
#include <math.h>

// ---------------------------------------------------------------------------
// NormalDistributionChecker1D, round 4 — MLP-discriminating experiment.
// Pass 1: sum/sumsq. 2048 blocks x 256; each thread owns exactly 8 float4,
//   loaded into 8 NAMED scalars back-to-back BEFORE any consumption.
// Pass 2: naive 9-sigmoid (band trick r3 regressed: scatter bookkeeping +
//   LDS gather cost more than the saved exp2s). 8 named prefetch float4,
//   then 288 unrolled sigmoid evals per thread. No LDS in the hot path.
// Pass 3: scalar fp64 epilogue.
// Accumulation: fp32 per-thread -> fp64 wave/block reduce -> fixed-point
// (x 2^20) int64 atomics (deterministic across graph replays).
// ---------------------------------------------------------------------------

#if __has_builtin(__builtin_amdgcn_exp2f)
#define EXP2F(x) __builtin_amdgcn_exp2f(x)
#else
#define EXP2F(x) exp2f(x)
#endif
#if __has_builtin(__builtin_amdgcn_rcpf)
#define RCPF(x) __builtin_amdgcn_rcpf(x)
#else
#define RCPF(x) (1.0f / (x))
#endif

#define FIXED_SCALE 1048576.0  // 2^20

static __device__ __forceinline__ double wave_reduce_d(double v) {
#pragma unroll
    for (int off = 32; off > 0; off >>= 1) v += __shfl_down(v, off);
    return v;
}

static __device__ __forceinline__ void atomic_add_fixed(long long* addr, double v) {
    long long q = (long long)llround(v * FIXED_SCALE);
    atomicAdd((unsigned long long*)addr, (unsigned long long)q);
}

// ws layout (long long): [0]=sum [1]=sumsq [2..10]=cum[0..8]
__global__ __launch_bounds__(256) void pass1_stats(const float* __restrict__ x,
                                                   long long* __restrict__ ws, int n) {
    const int tx = threadIdx.x;
    const int tid = blockIdx.x * 256 + tx;
    const int nthreads = gridDim.x * 256;
    const int n4 = n >> 2;
    const float4* __restrict__ x4 = (const float4*)x;

    float fs = 0.f, fss = 0.f;
    int i = tid;

    // Exactly one batch of 8 when n4 == 8*nthreads (true at n=16.7M, 2048 blk).
    // 8 independent named loads issued before ANY use -> 8-deep MLP per wave.
    if (i + 7 * nthreads < n4) {
        const float4 r0 = x4[i];
        const float4 r1 = x4[i + nthreads];
        const float4 r2 = x4[i + 2 * nthreads];
        const float4 r3 = x4[i + 3 * nthreads];
        const float4 r4 = x4[i + 4 * nthreads];
        const float4 r5 = x4[i + 5 * nthreads];
        const float4 r6 = x4[i + 6 * nthreads];
        const float4 r7 = x4[i + 7 * nthreads];
        i += 8 * nthreads;
        fs += (r0.x + r0.y) + (r0.z + r0.w);
        fss = fmaf(r0.x, r0.x, fss); fss = fmaf(r0.y, r0.y, fss);
        fss = fmaf(r0.z, r0.z, fss); fss = fmaf(r0.w, r0.w, fss);
        fs += (r1.x + r1.y) + (r1.z + r1.w);
        fss = fmaf(r1.x, r1.x, fss); fss = fmaf(r1.y, r1.y, fss);
        fss = fmaf(r1.z, r1.z, fss); fss = fmaf(r1.w, r1.w, fss);
        fs += (r2.x + r2.y) + (r2.z + r2.w);
        fss = fmaf(r2.x, r2.x, fss); fss = fmaf(r2.y, r2.y, fss);
        fss = fmaf(r2.z, r2.z, fss); fss = fmaf(r2.w, r2.w, fss);
        fs += (r3.x + r3.y) + (r3.z + r3.w);
        fss = fmaf(r3.x, r3.x, fss); fss = fmaf(r3.y, r3.y, fss);
        fss = fmaf(r3.z, r3.z, fss); fss = fmaf(r3.w, r3.w, fss);
        fs += (r4.x + r4.y) + (r4.z + r4.w);
        fss = fmaf(r4.x, r4.x, fss); fss = fmaf(r4.y, r4.y, fss);
        fss = fmaf(r4.z, r4.z, fss); fss = fmaf(r4.w, r4.w, fss);
        fs += (r5.x + r5.y) + (r5.z + r5.w);
        fss = fmaf(r5.x, r5.x, fss); fss = fmaf(r5.y, r5.y, fss);
        fss = fmaf(r5.z, r5.z, fss); fss = fmaf(r5.w, r5.w, fss);
        fs += (r6.x + r6.y) + (r6.z + r6.w);
        fss = fmaf(r6.x, r6.x, fss); fss = fmaf(r6.y, r6.y, fss);
        fss = fmaf(r6.z, r6.z, fss); fss = fmaf(r6.w, r6.w, fss);
        fs += (r7.x + r7.y) + (r7.z + r7.w);
        fss = fmaf(r7.x, r7.x, fss); fss = fmaf(r7.y, r7.y, fss);
        fss = fmaf(r7.z, r7.z, fss); fss = fmaf(r7.w, r7.w, fss);
    }
    for (; i < n4; i += nthreads) {  // residual (not taken at n=16.7M)
        float4 v = x4[i];
        fs += (v.x + v.y) + (v.z + v.w);
        fss = fmaf(v.x, v.x, fss); fss = fmaf(v.y, v.y, fss);
        fss = fmaf(v.z, v.z, fss); fss = fmaf(v.w, v.w, fss);
    }
    if (blockIdx.x == 0 && tx == 0) {  // n%4 scalar tail (empty at n=16.7M)
        for (int j = n4 << 2; j < n; ++j) {
            float v = x[j];
            fs += v;
            fss = fmaf(v, v, fss);
        }
    }

    double s = wave_reduce_d((double)fs);
    double ss = wave_reduce_d((double)fss);
    __shared__ double sm[4][2];
    const int lane = tx & 63, wid = tx >> 6;
    if (lane == 0) { sm[wid][0] = s; sm[wid][1] = ss; }
    __syncthreads();
    if (tx == 0) {
        double ts = 0, tss = 0;
#pragma unroll
        for (int w = 0; w < 4; ++w) { ts += sm[w][0]; tss += sm[w][1]; }
        atomic_add_fixed(&ws[0], ts);
        atomic_add_fixed(&ws[1], tss);
    }
}

__global__ __launch_bounds__(256) void pass2_cum(const float* __restrict__ x,
                                                 const long long* __restrict__ ws_stats,
                                                 long long* __restrict__ ws, int n) {
    // thresholds in a-units: C_k = 144.26950408889634 * zscore_k
    constexpr float C0 = -184.888834f, C1 = -121.420293f, C2 = -75.655000f,
                    C3 = -36.550261f, C4 = 0.0f, C5 = 36.550261f,
                    C6 = 75.655000f, C7 = 121.420293f, C8 = 184.888834f;

    // Stats computed once per block (fp64), broadcast via LDS.
    __shared__ float sSB[2];
    if (threadIdx.x == 0) {
        const double Ld = 144.26950408889634;  // 100 * log2(e)
        const double nd = (double)n;
        const double s = (double)ws_stats[0] / FIXED_SCALE;
        const double ss = (double)ws_stats[1] / FIXED_SCALE;
        const double mean = s / nd;
        const double var = (ss - s * s / nd) / (nd - 1.0);  // ddof=1
        const double inv_std = 1.0 / sqrt(var);
        sSB[0] = (float)(Ld * inv_std);
        sSB[1] = (float)(-Ld * inv_std * mean);
    }
    __syncthreads();
    const float S = sSB[0], B = sSB[1];

    float acc[9];
#pragma unroll
    for (int k = 0; k < 9; ++k) acc[k] = 0.f;

    auto process = [&](float xv) {
        const float a = fmaf(xv, S, B);  // a = 144.27 * z
        // 9 independent sigmoid chains; exp2 under/overflow saturates exactly
        // (rcp(1+inf)=0, rcp(1+0)=1).
        acc[0] += RCPF(1.0f + EXP2F(a - C0));
        acc[1] += RCPF(1.0f + EXP2F(a - C1));
        acc[2] += RCPF(1.0f + EXP2F(a - C2));
        acc[3] += RCPF(1.0f + EXP2F(a - C3));
        acc[4] += RCPF(1.0f + EXP2F(a - C4));
        acc[5] += RCPF(1.0f + EXP2F(a - C5));
        acc[6] += RCPF(1.0f + EXP2F(a - C6));
        acc[7] += RCPF(1.0f + EXP2F(a - C7));
        acc[8] += RCPF(1.0f + EXP2F(a - C8));
    };

    const int tx = threadIdx.x;
    const int tid = blockIdx.x * 256 + tx;
    const int nthreads = gridDim.x * 256;
    const int n4 = n >> 2;
    const float4* __restrict__ x4 = (const float4*)x;

    int i = tid;
    if (i + 7 * nthreads < n4) {  // exactly one batch of 8 at n=16.7M
        const float4 r0 = x4[i];
        const float4 r1 = x4[i + nthreads];
        const float4 r2 = x4[i + 2 * nthreads];
        const float4 r3 = x4[i + 3 * nthreads];
        const float4 r4 = x4[i + 4 * nthreads];
        const float4 r5 = x4[i + 5 * nthreads];
        const float4 r6 = x4[i + 6 * nthreads];
        const float4 r7 = x4[i + 7 * nthreads];
        i += 8 * nthreads;
        process(r0.x); process(r0.y); process(r0.z); process(r0.w);
        process(r1.x); process(r1.y); process(r1.z); process(r1.w);
        process(r2.x); process(r2.y); process(r2.z); process(r2.w);
        process(r3.x); process(r3.y); process(r3.z); process(r3.w);
        process(r4.x); process(r4.y); process(r4.z); process(r4.w);
        process(r5.x); process(r5.y); process(r5.z); process(r5.w);
        process(r6.x); process(r6.y); process(r6.z); process(r6.w);
        process(r7.x); process(r7.y); process(r7.z); process(r7.w);
    }
    for (; i < n4; i += nthreads) {  // residual (not taken at n=16.7M)
        float4 v = x4[i];
        process(v.x); process(v.y); process(v.z); process(v.w);
    }
    if (blockIdx.x == 0 && tx == 0) {  // n%4 scalar tail (empty at n=16.7M)
        for (int jj = n4 << 2; jj < n; ++jj) process(x[jj]);
    }

    __shared__ double sm[4][9];
    const int lane = tx & 63, wid = tx >> 6;
#pragma unroll
    for (int k = 0; k < 9; ++k) {
        double r = wave_reduce_d((double)acc[k]);
        if (lane == 0) sm[wid][k] = r;
    }
    __syncthreads();
    if (tx < 9) {
        double t = sm[0][tx] + sm[1][tx] + sm[2][tx] + sm[3][tx];
        atomic_add_fixed(&ws[2 + tx], t);
    }
}

__global__ void finalize_kernel(const long long* __restrict__ ws, float* __restrict__ out,
                                int n) {
    const double CRIT[9] = {14.683657, 12.242145, 10.656372, 9.413640, 8.342832,
                            7.357034,  6.393306,  5.380053,  4.168159};
    const double nd = (double)n;
    double cum[9];
#pragma unroll
    for (int k = 0; k < 9; ++k) cum[k] = (double)ws[2 + k] / FIXED_SCALE;

    double actual[10];
    actual[0] = cum[0];
#pragma unroll
    for (int k = 1; k < 9; ++k) actual[k] = cum[k] - cum[k - 1];
    actual[9] = nd - cum[8];

    const double expected = nd * (double)0.1f;
    const double denom = expected + 1e-7;
    double chi2 = 0.0;
#pragma unroll
    for (int j = 0; j < 10; ++j) {
        double d = actual[j] - expected;
        chi2 += d * d / denom;
    }

    double dneg[9], m = -1e300;
#pragma unroll
    for (int k = 0; k < 9; ++k) {
        dneg[k] = -fabs(chi2 - CRIT[k]);
        if (dneg[k] > m) m = dneg[k];
    }
    double W = 0.0, PQ = 0.0;
#pragma unroll
    for (int k = 0; k < 9; ++k) {
        double w = exp(dneg[k] - m);
        W += w;
        PQ += w * (0.1 * (double)(k + 1));
    }
    double p = 1.0 - PQ / W;
    double excess = (chi2 - 14.683657) / 100.0;
    if (excess < 0.0) excess = 0.0;
    out[0] = (float)(p + excess);
}

extern "C" void kernel_launch(void* const* d_in, const int* in_sizes, int n_in,
                              void* d_out, int out_size, void* d_ws, size_t ws_size,
                              hipStream_t stream) {
    const float* x = (const float*)d_in[0];
    const int n = in_sizes[0];
    long long* ws = (long long*)d_ws;

    hipMemsetAsync(d_ws, 0, 16 * sizeof(long long), stream);

    // 2048 blocks = 8 blocks/CU = 32 waves/CU; exactly 8 float4/thread.
    pass1_stats<<<2048, 256, 0, stream>>>(x, ws, n);
    pass2_cum<<<2048, 256, 0, stream>>>(x, ws, ws, n);
    finalize_kernel<<<1, 1, 0, stream>>>(ws, (float*)d_out, n);
}

// Round 5
// 130.311 us; speedup vs baseline: 1.4278x; 1.2975x over previous
//
#include <hip/hip_runtime.h>
#include <math.h>

// ---------------------------------------------------------------------------
// NormalDistributionChecker1D, round 5 — kill the same-address atomic tail.
// Theory: r1-r4 pass durations scale with #blocks (1024->41us, 2048->56us),
// VALUBusy ~3%, occupancy ~33%: the same-line device atomicAdds at block end
// serialize at the coherence point (~27-40ns each) and dominate everything.
// Fix: NO global atomics. Blocks plain-store partials to private slots;
// 1-block kernels reduce them in fp64 (fixed order -> deterministic).
//   pass1_stats   (1024 blk): sum/sumsq partials -> part1[2b..]
//   reduce_stats  (1 blk)   : 32KB read, compute S,B -> sb[]
//   pass2_cum     (1024 blk): 9-sigmoid soft CDF partials -> part2[9b..]
//   finalize      (1 blk)   : 72KB read, chi2 + softmax epilogue -> out
// Cross-XCD visibility: kernel-boundary release/acquire on one stream.
// ---------------------------------------------------------------------------

#if __has_builtin(__builtin_amdgcn_exp2f)
#define EXP2F(x) __builtin_amdgcn_exp2f(x)
#else
#define EXP2F(x) exp2f(x)
#endif
#if __has_builtin(__builtin_amdgcn_rcpf)
#define RCPF(x) __builtin_amdgcn_rcpf(x)
#else
#define RCPF(x) (1.0f / (x))
#endif

#define NBLK 1024  // 4 blocks/CU, 16 waves/CU: TLP 16KB/CU in flight >> 9KB needed

static __device__ __forceinline__ double wave_reduce_d(double v) {
#pragma unroll
    for (int off = 32; off > 0; off >>= 1) v += __shfl_down(v, off);
    return v;
}

// ws layout (double): [0..2*NBLK) part1 | [2*NBLK..2*NBLK+9*NBLK) part2 | then 2 floats S,B
__global__ __launch_bounds__(256) void pass1_stats(const float* __restrict__ x,
                                                   double* __restrict__ part1, int n) {
    const int tx = threadIdx.x;
    const int tid = blockIdx.x * 256 + tx;
    const int nthreads = NBLK * 256;
    const int n4 = n >> 2;
    const float4* __restrict__ x4 = (const float4*)x;

    float fs = 0.f, fss = 0.f;
    for (int i = tid; i < n4; i += nthreads) {  // 16 iters at n=16.7M
        float4 v = x4[i];
        fs += (v.x + v.y) + (v.z + v.w);
        fss = fmaf(v.x, v.x, fss); fss = fmaf(v.y, v.y, fss);
        fss = fmaf(v.z, v.z, fss); fss = fmaf(v.w, v.w, fss);
    }
    if (blockIdx.x == 0 && tx == 0) {  // n%4 scalar tail (empty at n=16.7M)
        for (int j = n4 << 2; j < n; ++j) {
            float v = x[j];
            fs += v;
            fss = fmaf(v, v, fss);
        }
    }

    double s = wave_reduce_d((double)fs);
    double ss = wave_reduce_d((double)fss);
    __shared__ double sm[4][2];
    const int lane = tx & 63, wid = tx >> 6;
    if (lane == 0) { sm[wid][0] = s; sm[wid][1] = ss; }
    __syncthreads();
    if (tx == 0) {
        double ts = (sm[0][0] + sm[1][0]) + (sm[2][0] + sm[3][0]);
        double tss = (sm[0][1] + sm[1][1]) + (sm[2][1] + sm[3][1]);
        part1[2 * blockIdx.x] = ts;       // plain store — no atomic
        part1[2 * blockIdx.x + 1] = tss;
    }
}

__global__ __launch_bounds__(256) void reduce_stats(const double* __restrict__ part1,
                                                    float* __restrict__ sb, int n) {
    const int tx = threadIdx.x;
    double s = 0.0, ss = 0.0;
    for (int b = tx; b < NBLK; b += 256) {  // fixed order -> deterministic
        s += part1[2 * b];
        ss += part1[2 * b + 1];
    }
    double rs = wave_reduce_d(s);
    double rss = wave_reduce_d(ss);
    __shared__ double sm[4][2];
    const int lane = tx & 63, wid = tx >> 6;
    if (lane == 0) { sm[wid][0] = rs; sm[wid][1] = rss; }
    __syncthreads();
    if (tx == 0) {
        double ts = (sm[0][0] + sm[1][0]) + (sm[2][0] + sm[3][0]);
        double tss = (sm[0][1] + sm[1][1]) + (sm[2][1] + sm[3][1]);
        const double Ld = 144.26950408889634;  // 100 * log2(e)
        const double nd = (double)n;
        const double mean = ts / nd;
        const double var = (tss - ts * ts / nd) / (nd - 1.0);  // ddof=1
        const double inv_std = 1.0 / sqrt(var);
        sb[0] = (float)(Ld * inv_std);          // S
        sb[1] = (float)(-Ld * inv_std * mean);  // B
    }
}

__global__ __launch_bounds__(256) void pass2_cum(const float* __restrict__ x,
                                                 const float* __restrict__ sb,
                                                 double* __restrict__ part2, int n) {
    constexpr float C0 = -184.888834f, C1 = -121.420293f, C2 = -75.655000f,
                    C3 = -36.550261f, C4 = 0.0f, C5 = 36.550261f,
                    C6 = 75.655000f, C7 = 121.420293f, C8 = 184.888834f;
    const float S = sb[0], B = sb[1];  // uniform scalar load

    float acc[9];
#pragma unroll
    for (int k = 0; k < 9; ++k) acc[k] = 0.f;

    auto process = [&](float xv) {
        const float a = fmaf(xv, S, B);  // a = 144.27 * z
        // exp2 under/overflow saturates exactly: rcp(1+inf)=0, rcp(1+0)=1.
        acc[0] += RCPF(1.0f + EXP2F(a - C0));
        acc[1] += RCPF(1.0f + EXP2F(a - C1));
        acc[2] += RCPF(1.0f + EXP2F(a - C2));
        acc[3] += RCPF(1.0f + EXP2F(a - C3));
        acc[4] += RCPF(1.0f + EXP2F(a - C4));
        acc[5] += RCPF(1.0f + EXP2F(a - C5));
        acc[6] += RCPF(1.0f + EXP2F(a - C6));
        acc[7] += RCPF(1.0f + EXP2F(a - C7));
        acc[8] += RCPF(1.0f + EXP2F(a - C8));
    };

    const int tx = threadIdx.x;
    const int tid = blockIdx.x * 256 + tx;
    const int nthreads = NBLK * 256;
    const int n4 = n >> 2;
    const float4* __restrict__ x4 = (const float4*)x;

    for (int i = tid; i < n4; i += nthreads) {  // 16 iters at n=16.7M
        float4 v = x4[i];
        process(v.x); process(v.y); process(v.z); process(v.w);
    }
    if (blockIdx.x == 0 && tx == 0) {  // n%4 scalar tail (empty at n=16.7M)
        for (int jj = n4 << 2; jj < n; ++jj) process(x[jj]);
    }

    __shared__ double sm[4][9];
    const int lane = tx & 63, wid = tx >> 6;
#pragma unroll
    for (int k = 0; k < 9; ++k) {
        double r = wave_reduce_d((double)acc[k]);
        if (lane == 0) sm[wid][k] = r;
    }
    __syncthreads();
    if (tx < 9) {
        double t = (sm[0][tx] + sm[1][tx]) + (sm[2][tx] + sm[3][tx]);
        part2[9 * blockIdx.x + tx] = t;  // plain store — no atomic
    }
}

__global__ __launch_bounds__(256) void finalize_kernel(const double* __restrict__ part2,
                                                       float* __restrict__ out, int n) {
    const int tx = threadIdx.x;
    double acc[9];
#pragma unroll
    for (int k = 0; k < 9; ++k) acc[k] = 0.0;
    for (int b = tx; b < NBLK; b += 256) {  // fixed order -> deterministic
#pragma unroll
        for (int k = 0; k < 9; ++k) acc[k] += part2[9 * b + k];
    }
    __shared__ double sm[4][9];
    const int lane = tx & 63, wid = tx >> 6;
#pragma unroll
    for (int k = 0; k < 9; ++k) {
        double r = wave_reduce_d(acc[k]);
        if (lane == 0) sm[wid][k] = r;
    }
    __syncthreads();
    if (tx == 0) {
        const double CRIT[9] = {14.683657, 12.242145, 10.656372, 9.413640, 8.342832,
                                7.357034,  6.393306,  5.380053,  4.168159};
        const double nd = (double)n;
        double cum[9];
#pragma unroll
        for (int k = 0; k < 9; ++k)
            cum[k] = (sm[0][k] + sm[1][k]) + (sm[2][k] + sm[3][k]);

        double actual[10];
        actual[0] = cum[0];
#pragma unroll
        for (int k = 1; k < 9; ++k) actual[k] = cum[k] - cum[k - 1];
        actual[9] = nd - cum[8];

        const double expected = nd * (double)0.1f;
        const double denom = expected + 1e-7;
        double chi2 = 0.0;
#pragma unroll
        for (int j = 0; j < 10; ++j) {
            double d = actual[j] - expected;
            chi2 += d * d / denom;
        }

        double dneg[9], m = -1e300;
#pragma unroll
        for (int k = 0; k < 9; ++k) {
            dneg[k] = -fabs(chi2 - CRIT[k]);
            if (dneg[k] > m) m = dneg[k];
        }
        double W = 0.0, PQ = 0.0;
#pragma unroll
        for (int k = 0; k < 9; ++k) {
            double w = exp(dneg[k] - m);
            W += w;
            PQ += w * (0.1 * (double)(k + 1));
        }
        double p = 1.0 - PQ / W;
        double excess = (chi2 - 14.683657) / 100.0;
        if (excess < 0.0) excess = 0.0;
        out[0] = (float)(p + excess);
    }
}

extern "C" void kernel_launch(void* const* d_in, const int* in_sizes, int n_in,
                              void* d_out, int out_size, void* d_ws, size_t ws_size,
                              hipStream_t stream) {
    const float* x = (const float*)d_in[0];
    const int n = in_sizes[0];

    double* part1 = (double*)d_ws;             // 2*NBLK doubles
    double* part2 = part1 + 2 * NBLK;          // 9*NBLK doubles
    float* sb = (float*)(part2 + 9 * NBLK);    // 2 floats (S, B)

    // No memset needed: every ws slot is written before it is read each call.
    pass1_stats<<<NBLK, 256, 0, stream>>>(x, part1, n);
    reduce_stats<<<1, 256, 0, stream>>>(part1, sb, n);
    pass2_cum<<<NBLK, 256, 0, stream>>>(x, sb, part2, n);
    finalize_kernel<<<1, 256, 0, stream>>>(part2, (float*)d_out, n);
}